// Round 16
// baseline (429.480 us; speedup 1.0000x reference)
//
#include <hip/hip_runtime.h>
#include <hip/hip_bf16.h>
#include <math.h>

#define B1 2048
#define B2 8192
#define NH 12
#define DH 64
#define DMODEL 768

typedef __attribute__((ext_vector_type(8))) short short8;
typedef __attribute__((ext_vector_type(4))) float floatx4;
typedef __attribute__((ext_vector_type(8))) unsigned short ushort8;
typedef __attribute__((ext_vector_type(4))) unsigned short ushort4v;

static __device__ __forceinline__ unsigned short f2bf(float f) {
  __bf16 b = (__bf16)f;
  return __builtin_bit_cast(unsigned short, b);
}

// ---------------------------------------------------------------------------
// f32-source bf16 MFMA GEMM tile: C[M,N] = bf16(A[M,K]) * bf16(B[N,K])^T.
// 128x128 tile, BK=32, 4 waves (2x2), 64x64/wave.
// LDS double-buffered, ONE barrier per k-step (R8/R13-verified invariant).
// Staging: reg-pipelined f32 loads one k-step ahead, cvt at write.
// L2N: per-64-col L2 norm epilogue.
// ---------------------------------------------------------------------------
template <bool L2N, bool F32OUT>
static __device__ __forceinline__ void gemm_tile_f32(
    const float* __restrict__ Ag, const float* __restrict__ Bg,
    void* __restrict__ Cv, int M, int N, int K, int m0, int n0,
    unsigned short* sA, unsigned short* sB) {  // each [2][4096] shorts
  const int tid = threadIdx.x;
  const int wave = tid >> 6;
  const int lane = tid & 63;
  const int wm = wave >> 1;
  const int wn = wave & 1;
  const int n15 = lane & 15;
  const int quad = lane >> 4;
  const int srow = lane >> 2;
  const int cpl = (lane & 3) ^ (srow >> 2);
  const int nstep = K >> 5;

  floatx4 acc[4][4];
#pragma unroll
  for (int i = 0; i < 4; ++i)
#pragma unroll
    for (int j = 0; j < 4; ++j) acc[i][j] = (floatx4){0.f, 0.f, 0.f, 0.f};

  float4 ar[2][2], br[2][2];
  // load k-step 0
#pragma unroll
  for (int jj = 0; jj < 2; ++jj) {
    const int row = (wave * 2 + jj) * 16 + srow;
    const size_t ga = (size_t)(m0 + row) * K + cpl * 8;
    const size_t gb = (size_t)(n0 + row) * K + cpl * 8;
    ar[jj][0] = *(const float4*)&Ag[ga];
    ar[jj][1] = *(const float4*)&Ag[ga + 4];
    br[jj][0] = *(const float4*)&Bg[gb];
    br[jj][1] = *(const float4*)&Bg[gb + 4];
  }
  // write buf0
#pragma unroll
  for (int jj = 0; jj < 2; ++jj) {
    const int j = wave * 2 + jj;
    const float4 a0 = ar[jj][0], a1 = ar[jj][1];
    const float4 b0 = br[jj][0], b1 = br[jj][1];
    ushort8 ah = {f2bf(a0.x), f2bf(a0.y), f2bf(a0.z), f2bf(a0.w),
                  f2bf(a1.x), f2bf(a1.y), f2bf(a1.z), f2bf(a1.w)};
    ushort8 bh = {f2bf(b0.x), f2bf(b0.y), f2bf(b0.z), f2bf(b0.w),
                  f2bf(b1.x), f2bf(b1.y), f2bf(b1.z), f2bf(b1.w)};
    *(ushort8*)&sA[j * 512 + lane * 8] = ah;
    *(ushort8*)&sB[j * 512 + lane * 8] = bh;
  }
  // load k-step 1
  if (nstep > 1) {
#pragma unroll
    for (int jj = 0; jj < 2; ++jj) {
      const int row = (wave * 2 + jj) * 16 + srow;
      const size_t ga = (size_t)(m0 + row) * K + 32 + cpl * 8;
      const size_t gb = (size_t)(n0 + row) * K + 32 + cpl * 8;
      ar[jj][0] = *(const float4*)&Ag[ga];
      ar[jj][1] = *(const float4*)&Ag[ga + 4];
      br[jj][0] = *(const float4*)&Bg[gb];
      br[jj][1] = *(const float4*)&Bg[gb + 4];
    }
  }
  __syncthreads();

  for (int k = 0; k < nstep; ++k) {
    const int cb = (k & 1) * 4096;
    if (k + 1 < nstep) {
      const int nb = ((k + 1) & 1) * 4096;
#pragma unroll
      for (int jj = 0; jj < 2; ++jj) {
        const int j = wave * 2 + jj;
        const float4 a0 = ar[jj][0], a1 = ar[jj][1];
        const float4 b0 = br[jj][0], b1 = br[jj][1];
        ushort8 ah = {f2bf(a0.x), f2bf(a0.y), f2bf(a0.z), f2bf(a0.w),
                      f2bf(a1.x), f2bf(a1.y), f2bf(a1.z), f2bf(a1.w)};
        ushort8 bh = {f2bf(b0.x), f2bf(b0.y), f2bf(b0.z), f2bf(b0.w),
                      f2bf(b1.x), f2bf(b1.y), f2bf(b1.z), f2bf(b1.w)};
        *(ushort8*)&sA[nb + j * 512 + lane * 8] = ah;
        *(ushort8*)&sB[nb + j * 512 + lane * 8] = bh;
      }
      if (k + 2 < nstep) {
#pragma unroll
        for (int jj = 0; jj < 2; ++jj) {
          const int row = (wave * 2 + jj) * 16 + srow;
          const size_t ga = (size_t)(m0 + row) * K + (k + 2) * 32 + cpl * 8;
          const size_t gb = (size_t)(n0 + row) * K + (k + 2) * 32 + cpl * 8;
          ar[jj][0] = *(const float4*)&Ag[ga];
          ar[jj][1] = *(const float4*)&Ag[ga + 4];
          br[jj][0] = *(const float4*)&Bg[gb];
          br[jj][1] = *(const float4*)&Bg[gb + 4];
        }
      }
    }

    short8 afh[4];
#pragma unroll
    for (int mt = 0; mt < 4; ++mt) {
      const int row = wm * 64 + mt * 16 + n15;
      afh[mt] = *(const short8*)&sA[cb + row * 32 + ((quad ^ (n15 >> 2)) << 3)];
    }
#pragma unroll
    for (int nt = 0; nt < 4; ++nt) {
      const int row = wn * 64 + nt * 16 + n15;
      const short8 bfh = *(const short8*)&sB[cb + row * 32 + ((quad ^ (n15 >> 2)) << 3)];
#pragma unroll
      for (int mt = 0; mt < 4; ++mt)
        acc[mt][nt] = __builtin_amdgcn_mfma_f32_16x16x32_bf16(afh[mt], bfh, acc[mt][nt], 0, 0, 0);
    }
    __syncthreads();  // publish next buf; parity readers of cb are done
  }

#pragma unroll
  for (int mt = 0; mt < 4; ++mt) {
    float scalev[4] = {1.f, 1.f, 1.f, 1.f};
    if constexpr (L2N) {
#pragma unroll
      for (int rr = 0; rr < 4; ++rr) {
        float ss = 0.f;
#pragma unroll
        for (int nt = 0; nt < 4; ++nt) ss += acc[mt][nt][rr] * acc[mt][nt][rr];
        ss += __shfl_xor(ss, 1, 64);
        ss += __shfl_xor(ss, 2, 64);
        ss += __shfl_xor(ss, 4, 64);
        ss += __shfl_xor(ss, 8, 64);
        scalev[rr] = 1.0f / fmaxf(sqrtf(ss), 1e-12f);
      }
    }
#pragma unroll
    for (int nt = 0; nt < 4; ++nt) {
#pragma unroll
      for (int rr = 0; rr < 4; ++rr) {
        const int row = m0 + wm * 64 + mt * 16 + quad * 4 + rr;
        const int col = n0 + wn * 64 + nt * 16 + n15;
        const float v = acc[mt][nt][rr] * scalev[rr];
        if constexpr (F32OUT)
          ((float*)Cv)[(size_t)row * N + col] = v;
        else
          ((unsigned short*)Cv)[(size_t)row * N + col] = f2bf(v);
      }
    }
  }
}

// ---------------------------------------------------------------------------
// Fused q+k+v projections, one launch (864 blocks), f32 sources.
// Segment-local XCD swizzle (R14-verified); v-GEMM n-major (R15).
// [0,96) q (L2N) | [96,480) k (L2N) | [480,864) v.
// ---------------------------------------------------------------------------
__global__ __launch_bounds__(256) void qkv_proj(
    const float* __restrict__ x1, const float* __restrict__ Wq,
    const float* __restrict__ x2, const float* __restrict__ Wk,
    const float* __restrict__ Wv,
    unsigned short* __restrict__ qbf, unsigned short* __restrict__ kbf,
    unsigned short* __restrict__ vtbf) {
  __shared__ __align__(16) unsigned short sA[8192], sB[8192];  // 2 bufs each
  const int bid = blockIdx.x;
  if (bid < 96) {
    const int b = (bid & 7) * 12 + (bid >> 3);            // 96 = 8*12
    gemm_tile_f32<true, false>(x1, Wq, qbf, B1, DMODEL, DMODEL,
                               (b / 6) * 128, (b % 6) * 128, sA, sB);
  } else if (bid < 480) {
    const int lb = bid - 96;
    const int b = (lb & 7) * 48 + (lb >> 3);              // 384 = 8*48
    gemm_tile_f32<true, false>(x2, Wk, kbf, B2, DMODEL, DMODEL,
                               (b / 6) * 128, (b % 6) * 128, sA, sB);
  } else {
    const int lb = bid - 480;
    const int b = (lb & 7) * 48 + (lb >> 3);              // 384 = 8*48
    gemm_tile_f32<false, false>(Wv, x2, vtbf, DMODEL, B2, DMODEL,
                                (b % 6) * 128, (b / 6) * 128, sA, sB);
  }
}

// ---------------------------------------------------------------------------
// MFMA bf16 attention — R16: 8-WAVE blocks (512 thr), 4-way key split.
// Same 768 blocks / per-block work / 50176 B LDS as R8-R15, but waves/CU
// 12 -> 24 (6/SIMD): each wave owns 32 keys per 128-chunk (ksub 0..3),
// halving per-wave MFMA+softmax work and doubling latency-hiding TLP.
// All verified primitives kept: staging formulas (s = i*512+tid, 2 iters),
// K swizzle (keyrow&7 == n15&7 still: ksub*32 ≡ 0 mod 8), V granule
// ksub*4+quad, Ps wave-private round trip (PSTR 34 = 32 keys + pad),
// slab plain stores, XCD swizzle, KSPLIT=2, 1 barrier/chunk K dbuf.
// Epilogue: 4-way combine via 3 Osc slabs + lsc (49920 B <= 50176).
// ---------------------------------------------------------------------------
#define KC 128
#define KSPLIT 2
#define NCH (B2 / KSPLIT / KC)  // 32
#define PSTR 34

__global__ __launch_bounds__(512, 6) void attn_mfma(
    const unsigned short* __restrict__ qb, const unsigned short* __restrict__ kb,
    const unsigned short* __restrict__ vt, float* __restrict__ aoacc,
    float* __restrict__ lacc, const int* __restrict__ invt_p) {
  __shared__ __align__(16) unsigned short smem[25088];  // 50176 B
  // K dbuf: [2][128 keys][64 dims] at 0 / 8192 (shorts)
  unsigned short* Psl = smem + 16384;   // 8 waves x 32 x PSTR = 8704 shorts

  const int bid = blockIdx.x;                     // 0..767
  const int swz = (bid & 7) * 96 + (bid >> 3);    // bijective (768 % 8 == 0)
  const int zz = swz / 384;
  const int rem = swz - zz * 384;
  const int h = rem >> 5;
  const int q0 = (rem & 31) * 64;

  const float c2 = (float)invt_p[0] * 1.4426950408889634f;
  const int tid = threadIdx.x;          // 0..511
  const int wave = tid >> 6;            // 0..7
  const int lane = tid & 63;
  const int qsub = wave >> 2;           // 0..1 : 32 q rows each
  const int ksub = wave & 3;            // 0..3 : 32 keys of each 128-chunk
  const int n15 = lane & 15;
  const int quad = lane >> 4;
  const int kz0 = zz * (B2 / KSPLIT);

  unsigned short* Ps = &Psl[wave * 32 * PSTR];

  short8 qf[2][2];
#pragma unroll
  for (int qt = 0; qt < 2; ++qt)
#pragma unroll
    for (int ks = 0; ks < 2; ++ks) {
      const int qrow = q0 + qsub * 32 + qt * 16 + n15;
      qf[qt][ks] = *(const short8*)&qb[(size_t)qrow * DMODEL + h * DH + ks * 32 + quad * 8];
    }

  floatx4 oacc[2][4];
#pragma unroll
  for (int qt = 0; qt < 2; ++qt)
#pragma unroll
    for (int nt = 0; nt < 4; ++nt) oacc[qt][nt] = (floatx4){0.f, 0.f, 0.f, 0.f};
  float lsum[2] = {0.f, 0.f};

  const unsigned short* kbp = kb + (size_t)kz0 * DMODEL + h * DH;
  const unsigned short* vbp = vt + (size_t)(h * DH) * B2 + kz0;

  // prologue: load K chunk0 -> stage buf0 -> load K chunk1 -> barrier
  // (512 threads x 16B x 2 iters = 16 KB chunk)
  ushort8 kr[2];
#pragma unroll
  for (int i = 0; i < 2; ++i) {
    const int s = i * 512 + tid;
    const int key = s >> 3, cpk = s & 7, chk = cpk ^ (key & 7);
    kr[i] = *(const ushort8*)&kbp[(size_t)key * DMODEL + chk * 8];
  }
#pragma unroll
  for (int i = 0; i < 2; ++i) {
    const int s = i * 512 + tid;
    const int key = s >> 3, cpk = s & 7;
    *(ushort8*)&smem[key * 64 + cpk * 8] = kr[i];
  }
#pragma unroll
  for (int i = 0; i < 2; ++i) {
    const int s = i * 512 + tid;
    const int key = s >> 3, cpk = s & 7, chk = cpk ^ (key & 7);
    kr[i] = *(const ushort8*)&kbp[(size_t)(KC + key) * DMODEL + chk * 8];
  }
  __syncthreads();

  for (int c = 0; c < NCH; ++c) {
    unsigned short* Kb = &smem[(c & 1) * 8192];
    unsigned short* Kn = &smem[((c + 1) & 1) * 8192];
    const unsigned short* vc_ = vbp + c * KC;

    // early V issue for THIS chunk: this wave's 32 keys -> granule ksub*4+quad
    ushort8 vr[4];
#pragma unroll
    for (int nt = 0; nt < 4; ++nt)
      vr[nt] = *(const ushort8*)&vc_[
          (size_t)(nt * 16 + n15) * B2 + (ksub * 4 + quad) * 8];

    // stage chunk c+1 into the other buffer; load chunk c+2
    if (c + 1 < NCH) {
#pragma unroll
      for (int i = 0; i < 2; ++i) {
        const int s = i * 512 + tid;
        const int key = s >> 3, cpk = s & 7;
        *(ushort8*)&Kn[key * 64 + cpk * 8] = kr[i];
      }
      if (c + 2 < NCH) {
        const unsigned short* k2 = kbp + (size_t)(c + 2) * KC * DMODEL;
#pragma unroll
        for (int i = 0; i < 2; ++i) {
          const int s = i * 512 + tid;
          const int key = s >> 3, cpk = s & 7, chk = cpk ^ (key & 7);
          kr[i] = *(const ushort8*)&k2[(size_t)key * DMODEL + chk * 8];
        }
      }
    }

    // ---- QK^T from Kb: this wave's keys ksub*32 .. ksub*32+31 ----
#pragma unroll
    for (int kt = 0; kt < 2; ++kt) {
      floatx4 s0 = {0.f, 0.f, 0.f, 0.f}, s1 = {0.f, 0.f, 0.f, 0.f};
#pragma unroll
      for (int ks = 0; ks < 2; ++ks) {
        const int keyrow = ksub * 32 + kt * 16 + n15;   // keyrow&7 == n15&7
        const int cp = (ks * 4 + quad) ^ (n15 & 7);
        const short8 kf = *(const short8*)&Kb[keyrow * 64 + cp * 8];
        s0 = __builtin_amdgcn_mfma_f32_16x16x32_bf16(kf, qf[0][ks], s0, 0, 0, 0);
        s1 = __builtin_amdgcn_mfma_f32_16x16x32_bf16(kf, qf[1][ks], s1, 0, 0, 0);
      }
      ushort4v p0, p1;
#pragma unroll
      for (int r = 0; r < 4; ++r) {
        const float e0 = exp2f(fmaf(s0[r], c2, -c2));
        const float e1 = exp2f(fmaf(s1[r], c2, -c2));
        lsum[0] += e0;
        lsum[1] += e1;
        p0[r] = f2bf(e0);
        p1[r] = f2bf(e1);
      }
      *(ushort4v*)&Ps[(0 * 16 + n15) * PSTR + kt * 16 + quad * 4] = p0;
      *(ushort4v*)&Ps[(1 * 16 + n15) * PSTR + kt * 16 + quad * 4] = p1;
    }

    // ---- PV: single k-slot group (32 keys), A k-slot j = key quad*8+j ----
    {
      short8 pa[2];
#pragma unroll
      for (int qt = 0; qt < 2; ++qt)
        pa[qt] = *(const short8*)&Ps[(qt * 16 + n15) * PSTR + quad * 8];
#pragma unroll
      for (int nt = 0; nt < 4; ++nt) {
        const short8 vf = __builtin_bit_cast(short8, vr[nt]);
        oacc[0][nt] = __builtin_amdgcn_mfma_f32_16x16x32_bf16(pa[0], vf, oacc[0][nt], 0, 0, 0);
        oacc[1][nt] = __builtin_amdgcn_mfma_f32_16x16x32_bf16(pa[1], vf, oacc[1][nt], 0, 0, 0);
      }
    }

    __syncthreads();  // publish Kn; prior Kb readers done before next overwrite
  }

  // reduce lsum over quads (lane bits 4,5): every lane holds wave total
#pragma unroll
  for (int qt = 0; qt < 2; ++qt) {
    float v = lsum[qt];
    v += __shfl_xor(v, 16, 64);
    v += __shfl_xor(v, 32, 64);
    lsum[qt] = v;
  }

  float* aoz = aoacc + (size_t)zz * B1 * DMODEL;
  float* lz = lacc + (size_t)zz * B1 * NH;

  __syncthreads();
  float* Osc = (float*)smem;          // 3 slabs [64 q][64 d] f32 = 49152 B
  float* lsc = Osc + 3 * 4096;        // [3][64] f32 (total 49920 <= 50176)
  if (ksub != 0) {
    float* slab = Osc + (ksub - 1) * 4096;
#pragma unroll
    for (int qt = 0; qt < 2; ++qt)
#pragma unroll
      for (int nt = 0; nt < 4; ++nt)
#pragma unroll
        for (int r = 0; r < 4; ++r) {
          const int row = qsub * 32 + qt * 16 + quad * 4 + r;
          slab[row * 64 + nt * 16 + n15] = oacc[qt][nt][r];
        }
    if (quad == 0) {
      lsc[(ksub - 1) * 64 + qsub * 32 + n15] = lsum[0];
      lsc[(ksub - 1) * 64 + qsub * 32 + 16 + n15] = lsum[1];
    }
  }
  __syncthreads();
  if (ksub == 0) {
#pragma unroll
    for (int qt = 0; qt < 2; ++qt)
#pragma unroll
      for (int nt = 0; nt < 4; ++nt)
#pragma unroll
        for (int r = 0; r < 4; ++r) {
          const int row = qsub * 32 + qt * 16 + quad * 4 + r;
          const int cc = nt * 16 + n15;
          const float v = oacc[qt][nt][r] + Osc[row * 64 + cc] +
                          Osc[4096 + row * 64 + cc] + Osc[8192 + row * 64 + cc];
          aoz[(size_t)(q0 + row) * DMODEL + h * DH + cc] = v;
        }
    if (quad == 0) {
      const int b0 = qsub * 32 + n15;
      const int b1 = qsub * 32 + 16 + n15;
      lz[(size_t)(q0 + b0) * NH + h] =
          lsum[0] + lsc[b0] + lsc[64 + b0] + lsc[128 + b0];
      lz[(size_t)(q0 + b1) * NH + h] =
          lsum[1] + lsc[b1] + lsc[64 + b1] + lsc[128 + b1];
    }
  }
}

// ---------------------------------------------------------------------------
// Wo projection, SPLIT-K x3 (grid 288 = 3 kz slabs x 96 tiles) with
// single-barrier double-buffered staging and per-kz-segment XCD swizzle.
// A = (ao0+ao1)/lsum cvt bf16, B = bf16(Wo). Output slab kz, summed in l2norm.
// ---------------------------------------------------------------------------
__global__ __launch_bounds__(256) void wo_proj(
    const float* __restrict__ aoacc, const float* __restrict__ lacc,
    const float* __restrict__ Wo, float* __restrict__ woout) {
  __shared__ __align__(16) unsigned short sA[8192], sB[8192];
  const int bid = blockIdx.x;
  const int kz = bid / 96;
  const int lb = bid % 96;
  const int t = (lb & 7) * 12 + (lb >> 3);   // segment-local XCD swizzle
  const int m0 = (t / 6) * 128;
  const int n0 = (t % 6) * 128;
  const int kbase = kz * 256;
  const int nstep = 8;  // 256 / 32
  const int tid = threadIdx.x;
  const int wave = tid >> 6;
  const int lane = tid & 63;
  const int wm = wave >> 1;
  const int wn = wave & 1;
  const int n15 = lane & 15;
  const int quad = lane >> 4;
  const int srow = lane >> 2;
  const int cpl = (lane & 3) ^ (srow >> 2);

  const float* ao1 = aoacc + (size_t)B1 * DMODEL;
  const float* la1 = lacc + (size_t)B1 * NH;

  floatx4 acc[4][4];
#pragma unroll
  for (int i = 0; i < 4; ++i)
#pragma unroll
    for (int j = 0; j < 4; ++j) acc[i][j] = (floatx4){0.f, 0.f, 0.f, 0.f};

  float4 Aa[2][2], Ab[2][2], Bw[2][2];
  float lw[2];

#define WO_LOADSTEP(s)                                                        \
  {                                                                           \
    const int kk = kbase + (s) * 32;                                          \
    _Pragma("unroll") for (int jj = 0; jj < 2; ++jj) {                        \
      const int row = (wave * 2 + jj) * 16 + srow;                            \
      const size_t ga = (size_t)(m0 + row) * DMODEL + kk + cpl * 8;           \
      const size_t gb = (size_t)(n0 + row) * DMODEL + kk + cpl * 8;           \
      Aa[jj][0] = *(const float4*)&aoacc[ga];                                 \
      Aa[jj][1] = *(const float4*)&aoacc[ga + 4];                             \
      Ab[jj][0] = *(const float4*)&ao1[ga];                                   \
      Ab[jj][1] = *(const float4*)&ao1[ga + 4];                               \
      Bw[jj][0] = *(const float4*)&Wo[gb];                                    \
      Bw[jj][1] = *(const float4*)&Wo[gb + 4];                                \
      const int head = (kk + cpl * 8) >> 6;                                   \
      const int li = (m0 + row) * NH + head;                                  \
      lw[jj] = lacc[li] + la1[li];                                            \
    }                                                                         \
  }

#define WO_WRITEBUF(boff)                                                     \
  {                                                                           \
    _Pragma("unroll") for (int jj = 0; jj < 2; ++jj) {                        \
      const int j = wave * 2 + jj;                                            \
      const float inv = 1.0f / lw[jj];                                        \
      const float4 a0 = Aa[jj][0], a1 = Aa[jj][1];                            \
      const float4 b0 = Ab[jj][0], b1 = Ab[jj][1];                            \
      const float4 w0 = Bw[jj][0], w1 = Bw[jj][1];                            \
      ushort8 ah = {f2bf((a0.x + b0.x) * inv), f2bf((a0.y + b0.y) * inv),     \
                    f2bf((a0.z + b0.z) * inv), f2bf((a0.w + b0.w) * inv),     \
                    f2bf((a1.x + b1.x) * inv), f2bf((a1.y + b1.y) * inv),     \
                    f2bf((a1.z + b1.z) * inv), f2bf((a1.w + b1.w) * inv)};    \
      ushort8 bh = {f2bf(w0.x), f2bf(w0.y), f2bf(w0.z), f2bf(w0.w),           \
                    f2bf(w1.x), f2bf(w1.y), f2bf(w1.z), f2bf(w1.w)};          \
      *(ushort8*)&sA[(boff) + j * 512 + lane * 8] = ah;                       \
      *(ushort8*)&sB[(boff) + j * 512 + lane * 8] = bh;                       \
    }                                                                         \
  }

  WO_LOADSTEP(0);
  WO_WRITEBUF(0);
  WO_LOADSTEP(1);
  __syncthreads();

  for (int k = 0; k < nstep; ++k) {
    const int cb = (k & 1) * 4096;
    if (k + 1 < nstep) {
      const int nb = ((k + 1) & 1) * 4096;
      WO_WRITEBUF(nb);
      if (k + 2 < nstep) WO_LOADSTEP(k + 2);
    }

    short8 afh[4];
#pragma unroll
    for (int mt = 0; mt < 4; ++mt) {
      const int row = wm * 64 + mt * 16 + n15;
      afh[mt] = *(const short8*)&sA[cb + row * 32 + ((quad ^ (n15 >> 2)) << 3)];
    }
#pragma unroll
    for (int nt = 0; nt < 4; ++nt) {
      const int row = wn * 64 + nt * 16 + n15;
      const short8 bfh = *(const short8*)&sB[cb + row * 32 + ((quad ^ (n15 >> 2)) << 3)];
#pragma unroll
      for (int mt = 0; mt < 4; ++mt)
        acc[mt][nt] = __builtin_amdgcn_mfma_f32_16x16x32_bf16(afh[mt], bfh, acc[mt][nt], 0, 0, 0);
    }
    __syncthreads();
  }

  float* wslab = woout + (size_t)kz * B1 * DMODEL;
#pragma unroll
  for (int mt = 0; mt < 4; ++mt)
#pragma unroll
    for (int nt = 0; nt < 4; ++nt)
#pragma unroll
      for (int rr = 0; rr < 4; ++rr) {
        const int row = m0 + wm * 64 + mt * 16 + quad * 4 + rr;
        const int col = n0 + wn * 64 + nt * 16 + n15;
        wslab[(size_t)row * DMODEL + col] = acc[mt][nt][rr];
      }
#undef WO_LOADSTEP
#undef WO_WRITEBUF
}

// ---------------------------------------------------------------------------
// Final row l2norm, summing the 3 wo split-K slabs.
// ---------------------------------------------------------------------------
__global__ __launch_bounds__(256) void l2norm_rows768_out(
    const float* __restrict__ x, float* __restrict__ out) {
  const int row = blockIdx.x;
  const float* x0 = &x[(size_t)row * DMODEL];
  const float* x1s = x0 + (size_t)B1 * DMODEL;
  const float* x2s = x0 + 2 * (size_t)B1 * DMODEL;
  float ss = 0.0f;
  float vals[3];
#pragma unroll
  for (int i = 0; i < 3; ++i) {
    const int c = threadIdx.x + i * 256;
    vals[i] = x0[c] + x1s[c] + x2s[c];
    ss += vals[i] * vals[i];
  }
#pragma unroll
  for (int off = 32; off > 0; off >>= 1) ss += __shfl_xor(ss, off, 64);
  __shared__ float ws[4];
  if ((threadIdx.x & 63) == 0) ws[threadIdx.x >> 6] = ss;
  __syncthreads();
  const float tot = ws[0] + ws[1] + ws[2] + ws[3];
  const float sc = 1.0f / fmaxf(sqrtf(tot), 1e-12f);
  float* orow = &out[(size_t)row * DMODEL];
#pragma unroll
  for (int i = 0; i < 3; ++i) orow[threadIdx.x + i * 256] = vals[i] * sc;
}

// ---------------------------------------------------------------------------
extern "C" void kernel_launch(void* const* d_in, const int* in_sizes, int n_in,
                              void* d_out, int out_size, void* d_ws,
                              size_t ws_size, hipStream_t stream) {
  const float* x1 = (const float*)d_in[0];
  const float* x2 = (const float*)d_in[1];
  const float* Wq = (const float*)d_in[2];
  const float* Wk = (const float*)d_in[3];
  const float* Wv = (const float*)d_in[4];
  const float* Wo = (const float*)d_in[5];
  const int* invt = (const int*)d_in[6];
  float* outp = (float*)d_out;

  // workspace (bytes):
  //  aoacc 2 slabs   [0,        12582912)
  //  woout 3 slabs   [12582912, 31457280)  (slab1/2 overlay vt region,
  //                                         which is dead after attn)
  //  vt_bf           [18874368, 31457280)
  //  lacc 2 slabs    [32636928, 32833536)
  //  q_bf            [38535168, 41680896)
  //  k_bf            [41680896, 54263808)
  char* ws = (char*)d_ws;
  float* aoacc = (float*)(ws + 0);
  float* woout = (float*)(ws + 12582912);
  unsigned short* vt_bf = (unsigned short*)(ws + 18874368);
  float* lacc = (float*)(ws + 32636928);
  unsigned short* q_bf = (unsigned short*)(ws + 38535168);
  unsigned short* k_bf = (unsigned short*)(ws + 41680896);

  // 1) q+k+v projections (R15-frozen)
  qkv_proj<<<864, 256, 0, stream>>>(x1, Wq, x2, Wk, Wv, q_bf, k_bf, vt_bf);
  // 2) attention: 8-wave blocks, 4-way key split (waves/CU 12 -> 24)
  attn_mfma<<<768, 512, 0, stream>>>(q_bf, k_bf, vt_bf, aoacc, lacc, invt);
  // 3) Wo projection, split-K x3 (R15-frozen)
  wo_proj<<<288, 256, 0, stream>>>(aoacc, lacc, Wo, woout);
  // 4) final row l2norm over 3 slabs
  l2norm_rows768_out<<<B1, 256, 0, stream>>>(woout, outp);
}

// Round 17
// 313.429 us; speedup vs baseline: 1.3703x; 1.3703x over previous
//
#include <hip/hip_runtime.h>
#include <hip/hip_bf16.h>
#include <math.h>

#define B1 2048
#define B2 8192
#define NH 12
#define DH 64
#define DMODEL 768

typedef __attribute__((ext_vector_type(8))) short short8;
typedef __attribute__((ext_vector_type(4))) float floatx4;
typedef __attribute__((ext_vector_type(8))) unsigned short ushort8;
typedef __attribute__((ext_vector_type(4))) unsigned short ushort4v;

static __device__ __forceinline__ unsigned short f2bf(float f) {
  __bf16 b = (__bf16)f;
  return __builtin_bit_cast(unsigned short, b);
}

// ---------------------------------------------------------------------------
// f32-source bf16 MFMA GEMM tile: C[M,N] = bf16(A[M,K]) * bf16(B[N,K])^T.
// 128x128 tile, BK=32, 4 waves (2x2), 64x64/wave.
// LDS double-buffered, ONE barrier per k-step (R8/R13-verified invariant).
// Staging: reg-pipelined f32 loads one k-step ahead, cvt at write.
// L2N: per-64-col L2 norm epilogue.
// ---------------------------------------------------------------------------
template <bool L2N, bool F32OUT>
static __device__ __forceinline__ void gemm_tile_f32(
    const float* __restrict__ Ag, const float* __restrict__ Bg,
    void* __restrict__ Cv, int M, int N, int K, int m0, int n0,
    unsigned short* sA, unsigned short* sB) {  // each [2][4096] shorts
  const int tid = threadIdx.x;
  const int wave = tid >> 6;
  const int lane = tid & 63;
  const int wm = wave >> 1;
  const int wn = wave & 1;
  const int n15 = lane & 15;
  const int quad = lane >> 4;
  const int srow = lane >> 2;
  const int cpl = (lane & 3) ^ (srow >> 2);
  const int nstep = K >> 5;

  floatx4 acc[4][4];
#pragma unroll
  for (int i = 0; i < 4; ++i)
#pragma unroll
    for (int j = 0; j < 4; ++j) acc[i][j] = (floatx4){0.f, 0.f, 0.f, 0.f};

  float4 ar[2][2], br[2][2];
  // load k-step 0
#pragma unroll
  for (int jj = 0; jj < 2; ++jj) {
    const int row = (wave * 2 + jj) * 16 + srow;
    const size_t ga = (size_t)(m0 + row) * K + cpl * 8;
    const size_t gb = (size_t)(n0 + row) * K + cpl * 8;
    ar[jj][0] = *(const float4*)&Ag[ga];
    ar[jj][1] = *(const float4*)&Ag[ga + 4];
    br[jj][0] = *(const float4*)&Bg[gb];
    br[jj][1] = *(const float4*)&Bg[gb + 4];
  }
  // write buf0
#pragma unroll
  for (int jj = 0; jj < 2; ++jj) {
    const int j = wave * 2 + jj;
    const float4 a0 = ar[jj][0], a1 = ar[jj][1];
    const float4 b0 = br[jj][0], b1 = br[jj][1];
    ushort8 ah = {f2bf(a0.x), f2bf(a0.y), f2bf(a0.z), f2bf(a0.w),
                  f2bf(a1.x), f2bf(a1.y), f2bf(a1.z), f2bf(a1.w)};
    ushort8 bh = {f2bf(b0.x), f2bf(b0.y), f2bf(b0.z), f2bf(b0.w),
                  f2bf(b1.x), f2bf(b1.y), f2bf(b1.z), f2bf(b1.w)};
    *(ushort8*)&sA[j * 512 + lane * 8] = ah;
    *(ushort8*)&sB[j * 512 + lane * 8] = bh;
  }
  // load k-step 1
  if (nstep > 1) {
#pragma unroll
    for (int jj = 0; jj < 2; ++jj) {
      const int row = (wave * 2 + jj) * 16 + srow;
      const size_t ga = (size_t)(m0 + row) * K + 32 + cpl * 8;
      const size_t gb = (size_t)(n0 + row) * K + 32 + cpl * 8;
      ar[jj][0] = *(const float4*)&Ag[ga];
      ar[jj][1] = *(const float4*)&Ag[ga + 4];
      br[jj][0] = *(const float4*)&Bg[gb];
      br[jj][1] = *(const float4*)&Bg[gb + 4];
    }
  }
  __syncthreads();

  for (int k = 0; k < nstep; ++k) {
    const int cb = (k & 1) * 4096;
    if (k + 1 < nstep) {
      const int nb = ((k + 1) & 1) * 4096;
#pragma unroll
      for (int jj = 0; jj < 2; ++jj) {
        const int j = wave * 2 + jj;
        const float4 a0 = ar[jj][0], a1 = ar[jj][1];
        const float4 b0 = br[jj][0], b1 = br[jj][1];
        ushort8 ah = {f2bf(a0.x), f2bf(a0.y), f2bf(a0.z), f2bf(a0.w),
                      f2bf(a1.x), f2bf(a1.y), f2bf(a1.z), f2bf(a1.w)};
        ushort8 bh = {f2bf(b0.x), f2bf(b0.y), f2bf(b0.z), f2bf(b0.w),
                      f2bf(b1.x), f2bf(b1.y), f2bf(b1.z), f2bf(b1.w)};
        *(ushort8*)&sA[nb + j * 512 + lane * 8] = ah;
        *(ushort8*)&sB[nb + j * 512 + lane * 8] = bh;
      }
      if (k + 2 < nstep) {
#pragma unroll
        for (int jj = 0; jj < 2; ++jj) {
          const int row = (wave * 2 + jj) * 16 + srow;
          const size_t ga = (size_t)(m0 + row) * K + (k + 2) * 32 + cpl * 8;
          const size_t gb = (size_t)(n0 + row) * K + (k + 2) * 32 + cpl * 8;
          ar[jj][0] = *(const float4*)&Ag[ga];
          ar[jj][1] = *(const float4*)&Ag[ga + 4];
          br[jj][0] = *(const float4*)&Bg[gb];
          br[jj][1] = *(const float4*)&Bg[gb + 4];
        }
      }
    }

    short8 afh[4];
#pragma unroll
    for (int mt = 0; mt < 4; ++mt) {
      const int row = wm * 64 + mt * 16 + n15;
      afh[mt] = *(const short8*)&sA[cb + row * 32 + ((quad ^ (n15 >> 2)) << 3)];
    }
#pragma unroll
    for (int nt = 0; nt < 4; ++nt) {
      const int row = wn * 64 + nt * 16 + n15;
      const short8 bfh = *(const short8*)&sB[cb + row * 32 + ((quad ^ (n15 >> 2)) << 3)];
#pragma unroll
      for (int mt = 0; mt < 4; ++mt)
        acc[mt][nt] = __builtin_amdgcn_mfma_f32_16x16x32_bf16(afh[mt], bfh, acc[mt][nt], 0, 0, 0);
    }
    __syncthreads();  // publish next buf; parity readers of cb are done
  }

#pragma unroll
  for (int mt = 0; mt < 4; ++mt) {
    float scalev[4] = {1.f, 1.f, 1.f, 1.f};
    if constexpr (L2N) {
#pragma unroll
      for (int rr = 0; rr < 4; ++rr) {
        float ss = 0.f;
#pragma unroll
        for (int nt = 0; nt < 4; ++nt) ss += acc[mt][nt][rr] * acc[mt][nt][rr];
        ss += __shfl_xor(ss, 1, 64);
        ss += __shfl_xor(ss, 2, 64);
        ss += __shfl_xor(ss, 4, 64);
        ss += __shfl_xor(ss, 8, 64);
        scalev[rr] = 1.0f / fmaxf(sqrtf(ss), 1e-12f);
      }
    }
#pragma unroll
    for (int nt = 0; nt < 4; ++nt) {
#pragma unroll
      for (int rr = 0; rr < 4; ++rr) {
        const int row = m0 + wm * 64 + mt * 16 + quad * 4 + rr;
        const int col = n0 + wn * 64 + nt * 16 + n15;
        const float v = acc[mt][nt][rr] * scalev[rr];
        if constexpr (F32OUT)
          ((float*)Cv)[(size_t)row * N + col] = v;
        else
          ((unsigned short*)Cv)[(size_t)row * N + col] = f2bf(v);
      }
    }
  }
}

// ---------------------------------------------------------------------------
// Fused q+k+v projections, one launch (864 blocks), f32 sources.
// Segment-local XCD swizzle (R14-verified); v-GEMM n-major (R15).
// [0,96) q (L2N) | [96,480) k (L2N) | [480,864) v.
// ---------------------------------------------------------------------------
__global__ __launch_bounds__(256) void qkv_proj(
    const float* __restrict__ x1, const float* __restrict__ Wq,
    const float* __restrict__ x2, const float* __restrict__ Wk,
    const float* __restrict__ Wv,
    unsigned short* __restrict__ qbf, unsigned short* __restrict__ kbf,
    unsigned short* __restrict__ vtbf) {
  __shared__ __align__(16) unsigned short sA[8192], sB[8192];  // 2 bufs each
  const int bid = blockIdx.x;
  if (bid < 96) {
    const int b = (bid & 7) * 12 + (bid >> 3);            // 96 = 8*12
    gemm_tile_f32<true, false>(x1, Wq, qbf, B1, DMODEL, DMODEL,
                               (b / 6) * 128, (b % 6) * 128, sA, sB);
  } else if (bid < 480) {
    const int lb = bid - 96;
    const int b = (lb & 7) * 48 + (lb >> 3);              // 384 = 8*48
    gemm_tile_f32<true, false>(x2, Wk, kbf, B2, DMODEL, DMODEL,
                               (b / 6) * 128, (b % 6) * 128, sA, sB);
  } else {
    const int lb = bid - 480;
    const int b = (lb & 7) * 48 + (lb >> 3);              // 384 = 8*48
    gemm_tile_f32<false, false>(Wv, x2, vtbf, DMODEL, B2, DMODEL,
                                (b % 6) * 128, (b / 6) * 128, sA, sB);
  }
}

// ---------------------------------------------------------------------------
// MFMA bf16 attention — R17: 8-wave blocks (512 thr), 4-way key split,
// RELAXED register bound (R16's __launch_bounds__(512,6) forced VGPR=40
// -> massive scratch spill: WRITE 13->276 MB, FETCH 15->491 MB. Natural
// allocation for this kernel is ~70-85 VGPR, which still permits 6
// waves/SIMD; LDS (50176 B) allows 3 blocks x 8 waves = 24 waves/CU.)
// Everything else identical to R16 (which passed numerically).
// ---------------------------------------------------------------------------
#define KC 128
#define KSPLIT 2
#define NCH (B2 / KSPLIT / KC)  // 32
#define PSTR 34

__global__ __launch_bounds__(512, 3) void attn_mfma(
    const unsigned short* __restrict__ qb, const unsigned short* __restrict__ kb,
    const unsigned short* __restrict__ vt, float* __restrict__ aoacc,
    float* __restrict__ lacc, const int* __restrict__ invt_p) {
  __shared__ __align__(16) unsigned short smem[25088];  // 50176 B
  // K dbuf: [2][128 keys][64 dims] at 0 / 8192 (shorts)
  unsigned short* Psl = smem + 16384;   // 8 waves x 32 x PSTR = 8704 shorts

  const int bid = blockIdx.x;                     // 0..767
  const int swz = (bid & 7) * 96 + (bid >> 3);    // bijective (768 % 8 == 0)
  const int zz = swz / 384;
  const int rem = swz - zz * 384;
  const int h = rem >> 5;
  const int q0 = (rem & 31) * 64;

  const float c2 = (float)invt_p[0] * 1.4426950408889634f;
  const int tid = threadIdx.x;          // 0..511
  const int wave = tid >> 6;            // 0..7
  const int lane = tid & 63;
  const int qsub = wave >> 2;           // 0..1 : 32 q rows each
  const int ksub = wave & 3;            // 0..3 : 32 keys of each 128-chunk
  const int n15 = lane & 15;
  const int quad = lane >> 4;
  const int kz0 = zz * (B2 / KSPLIT);

  unsigned short* Ps = &Psl[wave * 32 * PSTR];

  short8 qf[2][2];
#pragma unroll
  for (int qt = 0; qt < 2; ++qt)
#pragma unroll
    for (int ks = 0; ks < 2; ++ks) {
      const int qrow = q0 + qsub * 32 + qt * 16 + n15;
      qf[qt][ks] = *(const short8*)&qb[(size_t)qrow * DMODEL + h * DH + ks * 32 + quad * 8];
    }

  floatx4 oacc[2][4];
#pragma unroll
  for (int qt = 0; qt < 2; ++qt)
#pragma unroll
    for (int nt = 0; nt < 4; ++nt) oacc[qt][nt] = (floatx4){0.f, 0.f, 0.f, 0.f};
  float lsum[2] = {0.f, 0.f};

  const unsigned short* kbp = kb + (size_t)kz0 * DMODEL + h * DH;
  const unsigned short* vbp = vt + (size_t)(h * DH) * B2 + kz0;

  // prologue: load K chunk0 -> stage buf0 -> load K chunk1 -> barrier
  // (512 threads x 16B x 2 iters = 16 KB chunk)
  ushort8 kr[2];
#pragma unroll
  for (int i = 0; i < 2; ++i) {
    const int s = i * 512 + tid;
    const int key = s >> 3, cpk = s & 7, chk = cpk ^ (key & 7);
    kr[i] = *(const ushort8*)&kbp[(size_t)key * DMODEL + chk * 8];
  }
#pragma unroll
  for (int i = 0; i < 2; ++i) {
    const int s = i * 512 + tid;
    const int key = s >> 3, cpk = s & 7;
    *(ushort8*)&smem[key * 64 + cpk * 8] = kr[i];
  }
#pragma unroll
  for (int i = 0; i < 2; ++i) {
    const int s = i * 512 + tid;
    const int key = s >> 3, cpk = s & 7, chk = cpk ^ (key & 7);
    kr[i] = *(const ushort8*)&kbp[(size_t)(KC + key) * DMODEL + chk * 8];
  }
  __syncthreads();

  for (int c = 0; c < NCH; ++c) {
    unsigned short* Kb = &smem[(c & 1) * 8192];
    unsigned short* Kn = &smem[((c + 1) & 1) * 8192];
    const unsigned short* vc_ = vbp + c * KC;

    // early V issue for THIS chunk: this wave's 32 keys -> granule ksub*4+quad
    ushort8 vr[4];
#pragma unroll
    for (int nt = 0; nt < 4; ++nt)
      vr[nt] = *(const ushort8*)&vc_[
          (size_t)(nt * 16 + n15) * B2 + (ksub * 4 + quad) * 8];

    // stage chunk c+1 into the other buffer; load chunk c+2
    if (c + 1 < NCH) {
#pragma unroll
      for (int i = 0; i < 2; ++i) {
        const int s = i * 512 + tid;
        const int key = s >> 3, cpk = s & 7;
        *(ushort8*)&Kn[key * 64 + cpk * 8] = kr[i];
      }
      if (c + 2 < NCH) {
        const unsigned short* k2 = kbp + (size_t)(c + 2) * KC * DMODEL;
#pragma unroll
        for (int i = 0; i < 2; ++i) {
          const int s = i * 512 + tid;
          const int key = s >> 3, cpk = s & 7, chk = cpk ^ (key & 7);
          kr[i] = *(const ushort8*)&k2[(size_t)key * DMODEL + chk * 8];
        }
      }
    }

    // ---- QK^T from Kb: this wave's keys ksub*32 .. ksub*32+31 ----
#pragma unroll
    for (int kt = 0; kt < 2; ++kt) {
      floatx4 s0 = {0.f, 0.f, 0.f, 0.f}, s1 = {0.f, 0.f, 0.f, 0.f};
#pragma unroll
      for (int ks = 0; ks < 2; ++ks) {
        const int keyrow = ksub * 32 + kt * 16 + n15;   // keyrow&7 == n15&7
        const int cp = (ks * 4 + quad) ^ (n15 & 7);
        const short8 kf = *(const short8*)&Kb[keyrow * 64 + cp * 8];
        s0 = __builtin_amdgcn_mfma_f32_16x16x32_bf16(kf, qf[0][ks], s0, 0, 0, 0);
        s1 = __builtin_amdgcn_mfma_f32_16x16x32_bf16(kf, qf[1][ks], s1, 0, 0, 0);
      }
      ushort4v p0, p1;
#pragma unroll
      for (int r = 0; r < 4; ++r) {
        const float e0 = exp2f(fmaf(s0[r], c2, -c2));
        const float e1 = exp2f(fmaf(s1[r], c2, -c2));
        lsum[0] += e0;
        lsum[1] += e1;
        p0[r] = f2bf(e0);
        p1[r] = f2bf(e1);
      }
      *(ushort4v*)&Ps[(0 * 16 + n15) * PSTR + kt * 16 + quad * 4] = p0;
      *(ushort4v*)&Ps[(1 * 16 + n15) * PSTR + kt * 16 + quad * 4] = p1;
    }

    // ---- PV: single k-slot group (32 keys), A k-slot j = key quad*8+j ----
    {
      short8 pa[2];
#pragma unroll
      for (int qt = 0; qt < 2; ++qt)
        pa[qt] = *(const short8*)&Ps[(qt * 16 + n15) * PSTR + quad * 8];
#pragma unroll
      for (int nt = 0; nt < 4; ++nt) {
        const short8 vf = __builtin_bit_cast(short8, vr[nt]);
        oacc[0][nt] = __builtin_amdgcn_mfma_f32_16x16x32_bf16(pa[0], vf, oacc[0][nt], 0, 0, 0);
        oacc[1][nt] = __builtin_amdgcn_mfma_f32_16x16x32_bf16(pa[1], vf, oacc[1][nt], 0, 0, 0);
      }
    }

    __syncthreads();  // publish Kn; prior Kb readers done before next overwrite
  }

  // reduce lsum over quads (lane bits 4,5): every lane holds wave total
#pragma unroll
  for (int qt = 0; qt < 2; ++qt) {
    float v = lsum[qt];
    v += __shfl_xor(v, 16, 64);
    v += __shfl_xor(v, 32, 64);
    lsum[qt] = v;
  }

  float* aoz = aoacc + (size_t)zz * B1 * DMODEL;
  float* lz = lacc + (size_t)zz * B1 * NH;

  __syncthreads();
  float* Osc = (float*)smem;          // 3 slabs [64 q][64 d] f32 = 49152 B
  float* lsc = Osc + 3 * 4096;        // [3][64] f32 (total 49920 <= 50176)
  if (ksub != 0) {
    float* slab = Osc + (ksub - 1) * 4096;
#pragma unroll
    for (int qt = 0; qt < 2; ++qt)
#pragma unroll
      for (int nt = 0; nt < 4; ++nt)
#pragma unroll
        for (int r = 0; r < 4; ++r) {
          const int row = qsub * 32 + qt * 16 + quad * 4 + r;
          slab[row * 64 + nt * 16 + n15] = oacc[qt][nt][r];
        }
    if (quad == 0) {
      lsc[(ksub - 1) * 64 + qsub * 32 + n15] = lsum[0];
      lsc[(ksub - 1) * 64 + qsub * 32 + 16 + n15] = lsum[1];
    }
  }
  __syncthreads();
  if (ksub == 0) {
#pragma unroll
    for (int qt = 0; qt < 2; ++qt)
#pragma unroll
      for (int nt = 0; nt < 4; ++nt)
#pragma unroll
        for (int r = 0; r < 4; ++r) {
          const int row = qsub * 32 + qt * 16 + quad * 4 + r;
          const int cc = nt * 16 + n15;
          const float v = oacc[qt][nt][r] + Osc[row * 64 + cc] +
                          Osc[4096 + row * 64 + cc] + Osc[8192 + row * 64 + cc];
          aoz[(size_t)(q0 + row) * DMODEL + h * DH + cc] = v;
        }
    if (quad == 0) {
      const int b0 = qsub * 32 + n15;
      const int b1 = qsub * 32 + 16 + n15;
      lz[(size_t)(q0 + b0) * NH + h] =
          lsum[0] + lsc[b0] + lsc[64 + b0] + lsc[128 + b0];
      lz[(size_t)(q0 + b1) * NH + h] =
          lsum[1] + lsc[b1] + lsc[64 + b1] + lsc[128 + b1];
    }
  }
}

// ---------------------------------------------------------------------------
// Wo projection, SPLIT-K x3 (grid 288 = 3 kz slabs x 96 tiles) with
// single-barrier double-buffered staging and per-kz-segment XCD swizzle.
// A = (ao0+ao1)/lsum cvt bf16, B = bf16(Wo). Output slab kz, summed in l2norm.
// ---------------------------------------------------------------------------
__global__ __launch_bounds__(256) void wo_proj(
    const float* __restrict__ aoacc, const float* __restrict__ lacc,
    const float* __restrict__ Wo, float* __restrict__ woout) {
  __shared__ __align__(16) unsigned short sA[8192], sB[8192];
  const int bid = blockIdx.x;
  const int kz = bid / 96;
  const int lb = bid % 96;
  const int t = (lb & 7) * 12 + (lb >> 3);   // segment-local XCD swizzle
  const int m0 = (t / 6) * 128;
  const int n0 = (t % 6) * 128;
  const int kbase = kz * 256;
  const int nstep = 8;  // 256 / 32
  const int tid = threadIdx.x;
  const int wave = tid >> 6;
  const int lane = tid & 63;
  const int wm = wave >> 1;
  const int wn = wave & 1;
  const int n15 = lane & 15;
  const int quad = lane >> 4;
  const int srow = lane >> 2;
  const int cpl = (lane & 3) ^ (srow >> 2);

  const float* ao1 = aoacc + (size_t)B1 * DMODEL;
  const float* la1 = lacc + (size_t)B1 * NH;

  floatx4 acc[4][4];
#pragma unroll
  for (int i = 0; i < 4; ++i)
#pragma unroll
    for (int j = 0; j < 4; ++j) acc[i][j] = (floatx4){0.f, 0.f, 0.f, 0.f};

  float4 Aa[2][2], Ab[2][2], Bw[2][2];
  float lw[2];

#define WO_LOADSTEP(s)                                                        \
  {                                                                           \
    const int kk = kbase + (s) * 32;                                          \
    _Pragma("unroll") for (int jj = 0; jj < 2; ++jj) {                        \
      const int row = (wave * 2 + jj) * 16 + srow;                            \
      const size_t ga = (size_t)(m0 + row) * DMODEL + kk + cpl * 8;           \
      const size_t gb = (size_t)(n0 + row) * DMODEL + kk + cpl * 8;           \
      Aa[jj][0] = *(const float4*)&aoacc[ga];                                 \
      Aa[jj][1] = *(const float4*)&aoacc[ga + 4];                             \
      Ab[jj][0] = *(const float4*)&ao1[ga];                                   \
      Ab[jj][1] = *(const float4*)&ao1[ga + 4];                               \
      Bw[jj][0] = *(const float4*)&Wo[gb];                                    \
      Bw[jj][1] = *(const float4*)&Wo[gb + 4];                                \
      const int head = (kk + cpl * 8) >> 6;                                   \
      const int li = (m0 + row) * NH + head;                                  \
      lw[jj] = lacc[li] + la1[li];                                            \
    }                                                                         \
  }

#define WO_WRITEBUF(boff)                                                     \
  {                                                                           \
    _Pragma("unroll") for (int jj = 0; jj < 2; ++jj) {                        \
      const int j = wave * 2 + jj;                                            \
      const float inv = 1.0f / lw[jj];                                        \
      const float4 a0 = Aa[jj][0], a1 = Aa[jj][1];                            \
      const float4 b0 = Ab[jj][0], b1 = Ab[jj][1];                            \
      const float4 w0 = Bw[jj][0], w1 = Bw[jj][1];                            \
      ushort8 ah = {f2bf((a0.x + b0.x) * inv), f2bf((a0.y + b0.y) * inv),     \
                    f2bf((a0.z + b0.z) * inv), f2bf((a0.w + b0.w) * inv),     \
                    f2bf((a1.x + b1.x) * inv), f2bf((a1.y + b1.y) * inv),     \
                    f2bf((a1.z + b1.z) * inv), f2bf((a1.w + b1.w) * inv)};    \
      ushort8 bh = {f2bf(w0.x), f2bf(w0.y), f2bf(w0.z), f2bf(w0.w),           \
                    f2bf(w1.x), f2bf(w1.y), f2bf(w1.z), f2bf(w1.w)};          \
      *(ushort8*)&sA[(boff) + j * 512 + lane * 8] = ah;                       \
      *(ushort8*)&sB[(boff) + j * 512 + lane * 8] = bh;                       \
    }                                                                         \
  }

  WO_LOADSTEP(0);
  WO_WRITEBUF(0);
  WO_LOADSTEP(1);
  __syncthreads();

  for (int k = 0; k < nstep; ++k) {
    const int cb = (k & 1) * 4096;
    if (k + 1 < nstep) {
      const int nb = ((k + 1) & 1) * 4096;
      WO_WRITEBUF(nb);
      if (k + 2 < nstep) WO_LOADSTEP(k + 2);
    }

    short8 afh[4];
#pragma unroll
    for (int mt = 0; mt < 4; ++mt) {
      const int row = wm * 64 + mt * 16 + n15;
      afh[mt] = *(const short8*)&sA[cb + row * 32 + ((quad ^ (n15 >> 2)) << 3)];
    }
#pragma unroll
    for (int nt = 0; nt < 4; ++nt) {
      const int row = wn * 64 + nt * 16 + n15;
      const short8 bfh = *(const short8*)&sB[cb + row * 32 + ((quad ^ (n15 >> 2)) << 3)];
#pragma unroll
      for (int mt = 0; mt < 4; ++mt)
        acc[mt][nt] = __builtin_amdgcn_mfma_f32_16x16x32_bf16(afh[mt], bfh, acc[mt][nt], 0, 0, 0);
    }
    __syncthreads();
  }

  float* wslab = woout + (size_t)kz * B1 * DMODEL;
#pragma unroll
  for (int mt = 0; mt < 4; ++mt)
#pragma unroll
    for (int nt = 0; nt < 4; ++nt)
#pragma unroll
      for (int rr = 0; rr < 4; ++rr) {
        const int row = m0 + wm * 64 + mt * 16 + quad * 4 + rr;
        const int col = n0 + wn * 64 + nt * 16 + n15;
        wslab[(size_t)row * DMODEL + col] = acc[mt][nt][rr];
      }
#undef WO_LOADSTEP
#undef WO_WRITEBUF
}

// ---------------------------------------------------------------------------
// Final row l2norm, summing the 3 wo split-K slabs.
// ---------------------------------------------------------------------------
__global__ __launch_bounds__(256) void l2norm_rows768_out(
    const float* __restrict__ x, float* __restrict__ out) {
  const int row = blockIdx.x;
  const float* x0 = &x[(size_t)row * DMODEL];
  const float* x1s = x0 + (size_t)B1 * DMODEL;
  const float* x2s = x0 + 2 * (size_t)B1 * DMODEL;
  float ss = 0.0f;
  float vals[3];
#pragma unroll
  for (int i = 0; i < 3; ++i) {
    const int c = threadIdx.x + i * 256;
    vals[i] = x0[c] + x1s[c] + x2s[c];
    ss += vals[i] * vals[i];
  }
#pragma unroll
  for (int off = 32; off > 0; off >>= 1) ss += __shfl_xor(ss, off, 64);
  __shared__ float ws[4];
  if ((threadIdx.x & 63) == 0) ws[threadIdx.x >> 6] = ss;
  __syncthreads();
  const float tot = ws[0] + ws[1] + ws[2] + ws[3];
  const float sc = 1.0f / fmaxf(sqrtf(tot), 1e-12f);
  float* orow = &out[(size_t)row * DMODEL];
#pragma unroll
  for (int i = 0; i < 3; ++i) orow[threadIdx.x + i * 256] = vals[i] * sc;
}

// ---------------------------------------------------------------------------
extern "C" void kernel_launch(void* const* d_in, const int* in_sizes, int n_in,
                              void* d_out, int out_size, void* d_ws,
                              size_t ws_size, hipStream_t stream) {
  const float* x1 = (const float*)d_in[0];
  const float* x2 = (const float*)d_in[1];
  const float* Wq = (const float*)d_in[2];
  const float* Wk = (const float*)d_in[3];
  const float* Wv = (const float*)d_in[4];
  const float* Wo = (const float*)d_in[5];
  const int* invt = (const int*)d_in[6];
  float* outp = (float*)d_out;

  // workspace (bytes):
  //  aoacc 2 slabs   [0,        12582912)
  //  woout 3 slabs   [12582912, 31457280)  (slab1/2 overlay vt region,
  //                                         which is dead after attn)
  //  vt_bf           [18874368, 31457280)
  //  lacc 2 slabs    [32636928, 32833536)
  //  q_bf            [38535168, 41680896)
  //  k_bf            [41680896, 54263808)
  char* ws = (char*)d_ws;
  float* aoacc = (float*)(ws + 0);
  float* woout = (float*)(ws + 12582912);
  unsigned short* vt_bf = (unsigned short*)(ws + 18874368);
  float* lacc = (float*)(ws + 32636928);
  unsigned short* q_bf = (unsigned short*)(ws + 38535168);
  unsigned short* k_bf = (unsigned short*)(ws + 41680896);

  // 1) q+k+v projections (R15-frozen)
  qkv_proj<<<864, 256, 0, stream>>>(x1, Wq, x2, Wk, Wv, q_bf, k_bf, vt_bf);
  // 2) attention: 8-wave blocks, 4-way key split, relaxed register bound
  attn_mfma<<<768, 512, 0, stream>>>(q_bf, k_bf, vt_bf, aoacc, lacc, invt);
  // 3) Wo projection, split-K x3 (R15-frozen)
  wo_proj<<<288, 256, 0, stream>>>(aoacc, lacc, Wo, woout);
  // 4) final row l2norm over 3 slabs
  l2norm_rows768_out<<<B1, 256, 0, stream>>>(woout, outp);
}